// Round 7
// baseline (235.971 us; speedup 1.0000x reference)
//
#include <hip/hip_runtime.h>
#include <math.h>

#define HD    128
#define NQH   32
#define NKVH  8
#define GQA   4
#define PBLK  16      // paged cache block size
#define MAXNB 512     // max block-table entries cached in LDS
#define CHUNK 256     // tokens per score chunk (= block size: lane-per-token)

#define L2_10000 13.287712379549449f   // log2(10000)

typedef float f4 __attribute__((ext_vector_type(4)));

// token base pointer (K or V) for token t; t == T means "current" k/v
__device__ __forceinline__ const float* tok_base(
    const float* __restrict__ cache, const float* __restrict__ cur,
    const int* __restrict__ btrow, int t, int T, int b, int h)
{
    if (t == T) return cur + ((size_t)b * NKVH + h) * HD;
    int blk = btrow[t >> 4];
    return cache + (((size_t)blk * PBLK + (t & (PBLK - 1))) * NKVH + h) * HD;
}

// row-major rope table: tab[t*128 + 2*f] = cos(t*invf[f]), [2*f+1] = sin
// f32 math matches the reference (jnp computes inv_freq/ang/cos in f32).
__global__ void rope_table_kernel(float* __restrict__ tab, int T) {
    int idx = blockIdx.x * blockDim.x + threadIdx.x;
    int total = (T + 1) * 64;
    if (idx >= total) return;
    int t = idx >> 6;
    int f = idx & 63;
    float invf = exp2f(-(float)f * (L2_10000 / 64.0f));
    float ss, cc;
    sincosf((float)t * invf, &ss, &cc);
    tab[(size_t)t * 128 + 2 * f]     = cc;
    tab[(size_t)t * 128 + 2 * f + 1] = ss;
}

// Lane-per-token phase-1: each thread owns one token, streams its K row and
// rope row, dots against LDS-broadcast roped-Q fully in-lane. Eliminates the
// per-token 5-stage shuffle chain + 4 VMEM/token that pinned rounds 2-6 at
// ~170us regardless of occupancy/grid (latency-bound on cross-lane DS chain).
__global__ __launch_bounds__(256) void paged_attn_kernel(
    const float* __restrict__ q,
    const float* __restrict__ kcur,
    const float* __restrict__ vcur,
    const float* __restrict__ kc,
    const float* __restrict__ vc,
    const int* __restrict__ bt,
    const float* __restrict__ tab,
    float* __restrict__ out,       // used when S == 1
    float* __restrict__ pm,        // [nblk][4]
    float* __restrict__ pl,        // [nblk][4]
    float* __restrict__ po,        // [nblk][4][HD]
    int T, int nb, int S, int useTable)
{
    const int bh = blockIdx.x / S;
    const int s  = blockIdx.x - bh * S;
    const int b  = bh >> 3;
    const int h  = bh & 7;
    const int tid = threadIdx.x;
    const int hw  = tid >> 5;        // half-wave id 0..7 (PV phase)
    const int il  = tid & 31;        // lane within half-wave
    const int d0v = il << 2;         // V/output dims [d0v, d0v+4)
    const int w   = tid >> 6;        // wave id 0..3

    const int total = T + 1;
    const int chunkT = (total + S - 1) / S;
    const int lo0   = s * chunkT;
    const int hi0   = min(lo0 + chunkT, total);

    __shared__ int   sbt[MAXNB];
    __shared__ float qlo[4 * 64];            // roped+scaled q, dims [0,64)  per head
    __shared__ float qhi[4 * 64];            // roped+scaled q, dims [64,128) per head
    __shared__ float sc[CHUNK * 4];          // scores / p for current chunk, [t][g]
    __shared__ float redM[4][4];
    __shared__ float redL[4][4];
    __shared__ float lodata[4][4][HD];

    // ---- stage block table + roped q ----
    const int* btrow = bt + (size_t)b * nb;
    if (nb <= MAXNB) {
        for (int i = tid; i < nb; i += 256) sbt[i] = btrow[i];
    }
    {
        // 256 threads = (g, f) pairs; each computes both lo and hi rotated vals
        const int g = tid >> 6;
        const int f = tid & 63;
        const float* qb = q + ((size_t)b * NQH + h * GQA + g) * HD;
        float xlo = qb[f];
        float xhi = qb[64 + f];
        float cc, ssn;
        if (useTable) {
            cc  = tab[(size_t)T * 128 + 2 * f];
            ssn = tab[(size_t)T * 128 + 2 * f + 1];
        } else {
            float invf = exp2f(-(float)f * (L2_10000 / 64.0f));
            sincosf((float)T * invf, &ssn, &cc);
        }
        const float scale = 0.08838834764831845f;  // 128^-0.5 folded into q
        qlo[g * 64 + f] = (xlo * cc - xhi * ssn) * scale;
        qhi[g * 64 + f] = (xhi * cc + xlo * ssn) * scale;
    }
    __syncthreads();
    if (nb <= MAXNB) btrow = sbt;

    // running state (redundant identical copies in every thread)
    float Mr0 = -INFINITY, Mr1 = -INFINITY, Mr2 = -INFINITY, Mr3 = -INFINITY;
    float Lr0 = 0.f, Lr1 = 0.f, Lr2 = 0.f, Lr3 = 0.f;
    f4 o[4] = {};

    const int gsm  = tid & 3;        // head for softmax-reduce phase
    const int idxm = tid >> 2;       // 0..63

    for (int clo = lo0; clo < hi0; clo += CHUNK) {
        const int chi = min(clo + CHUNK, hi0);
        const int cn  = chi - clo;

        // ========== phase 1: lane-per-token raw scores -> LDS ==========
        {
            const int t   = clo + tid;
            const bool act = (t < chi);
            const int tc  = act ? t : T;                 // clamp to a valid row
            const float* kb = tok_base(kc, kcur, btrow, tc, T, b, h);
            const float* tb = tab + (size_t)tc * 128;
            float a0 = 0.f, a1 = 0.f, a2 = 0.f, a3 = 0.f;
#pragma unroll 4
            for (int f0 = 0; f0 < 64; f0 += 4) {
                f4 klo = *(const f4*)(kb + f0);
                f4 khi = *(const f4*)(kb + 64 + f0);
                f4 cs0, cs1;
                if (useTable) {
                    cs0 = *(const f4*)(tb + 2 * f0);
                    cs1 = *(const f4*)(tb + 2 * f0 + 4);
                } else {
                    float ang, ssx, ccx;
                    float fbase = (float)tc;
#pragma unroll
                    for (int j = 0; j < 2; ++j) {
                        float invf = exp2f(-(float)(f0 + j) * (L2_10000 / 64.0f));
                        ang = fbase * invf; sincosf(ang, &ssx, &ccx);
                        if (j == 0) { cs0.x = ccx; cs0.y = ssx; }
                        else        { cs0.z = ccx; cs0.w = ssx; }
                    }
#pragma unroll
                    for (int j = 2; j < 4; ++j) {
                        float invf = exp2f(-(float)(f0 + j) * (L2_10000 / 64.0f));
                        ang = fbase * invf; sincosf(ang, &ssx, &ccx);
                        if (j == 2) { cs1.x = ccx; cs1.y = ssx; }
                        else        { cs1.z = ccx; cs1.w = ssx; }
                    }
                }
                f4 krlo, krhi;
                krlo.x = klo.x * cs0.x - khi.x * cs0.y;  krhi.x = khi.x * cs0.x + klo.x * cs0.y;
                krlo.y = klo.y * cs0.z - khi.y * cs0.w;  krhi.y = khi.y * cs0.z + klo.y * cs0.w;
                krlo.z = klo.z * cs1.x - khi.z * cs1.y;  krhi.z = khi.z * cs1.x + klo.z * cs1.y;
                krlo.w = klo.w * cs1.z - khi.w * cs1.w;  krhi.w = khi.w * cs1.z + klo.w * cs1.w;

                f4 ql, qh;
                ql = *(const f4*)&qlo[0 * 64 + f0];  qh = *(const f4*)&qhi[0 * 64 + f0];
                a0 += ql.x * krlo.x + ql.y * krlo.y + ql.z * krlo.z + ql.w * krlo.w
                    + qh.x * krhi.x + qh.y * krhi.y + qh.z * krhi.z + qh.w * krhi.w;
                ql = *(const f4*)&qlo[1 * 64 + f0];  qh = *(const f4*)&qhi[1 * 64 + f0];
                a1 += ql.x * krlo.x + ql.y * krlo.y + ql.z * krlo.z + ql.w * krlo.w
                    + qh.x * krhi.x + qh.y * krhi.y + qh.z * krhi.z + qh.w * krhi.w;
                ql = *(const f4*)&qlo[2 * 64 + f0];  qh = *(const f4*)&qhi[2 * 64 + f0];
                a2 += ql.x * krlo.x + ql.y * krlo.y + ql.z * krlo.z + ql.w * krlo.w
                    + qh.x * krhi.x + qh.y * krhi.y + qh.z * krhi.z + qh.w * krhi.w;
                ql = *(const f4*)&qlo[3 * 64 + f0];  qh = *(const f4*)&qhi[3 * 64 + f0];
                a3 += ql.x * krlo.x + ql.y * krlo.y + ql.z * krlo.z + ql.w * krlo.w
                    + qh.x * krhi.x + qh.y * krhi.y + qh.z * krhi.z + qh.w * krhi.w;
            }
            if (act) {
                f4 sv; sv.x = a0; sv.y = a1; sv.z = a2; sv.w = a3;
                *(f4*)&sc[(t - clo) * 4] = sv;
            }
        }
        __syncthreads();

        // ========== block softmax over the chunk ==========
        float pmax = -INFINITY;
        for (int tt = idxm; tt < cn; tt += 64) pmax = fmaxf(pmax, sc[tt * 4 + gsm]);
        pmax = fmaxf(pmax, __shfl_xor(pmax, 4));
        pmax = fmaxf(pmax, __shfl_xor(pmax, 8));
        pmax = fmaxf(pmax, __shfl_xor(pmax, 16));
        pmax = fmaxf(pmax, __shfl_xor(pmax, 32));
        if ((tid & 63) < 4) redM[w][tid & 3] = pmax;
        __syncthreads();

        const float Mn0 = fmaxf(Mr0, fmaxf(fmaxf(redM[0][0], redM[1][0]), fmaxf(redM[2][0], redM[3][0])));
        const float Mn1 = fmaxf(Mr1, fmaxf(fmaxf(redM[0][1], redM[1][1]), fmaxf(redM[2][1], redM[3][1])));
        const float Mn2 = fmaxf(Mr2, fmaxf(fmaxf(redM[0][2], redM[1][2]), fmaxf(redM[2][2], redM[3][2])));
        const float Mn3 = fmaxf(Mr3, fmaxf(fmaxf(redM[0][3], redM[1][3]), fmaxf(redM[2][3], redM[3][3])));

        const float Mg = (gsm == 0) ? Mn0 : (gsm == 1) ? Mn1 : (gsm == 2) ? Mn2 : Mn3;
        float lsum = 0.f;
        for (int tt = idxm; tt < cn; tt += 64) {
            float p = __expf(sc[tt * 4 + gsm] - Mg);
            sc[tt * 4 + gsm] = p;
            lsum += p;
        }
        lsum += __shfl_xor(lsum, 4);
        lsum += __shfl_xor(lsum, 8);
        lsum += __shfl_xor(lsum, 16);
        lsum += __shfl_xor(lsum, 32);
        if ((tid & 63) < 4) redL[w][tid & 3] = lsum;
        __syncthreads();

        {
            const float Lc0 = redL[0][0] + redL[1][0] + redL[2][0] + redL[3][0];
            const float Lc1 = redL[0][1] + redL[1][1] + redL[2][1] + redL[3][1];
            const float Lc2 = redL[0][2] + redL[1][2] + redL[2][2] + redL[3][2];
            const float Lc3 = redL[0][3] + redL[1][3] + redL[2][3] + redL[3][3];
            const float c0 = __expf(Mr0 - Mn0);   // first chunk: exp(-inf)=0
            const float c1 = __expf(Mr1 - Mn1);
            const float c2 = __expf(Mr2 - Mn2);
            const float c3 = __expf(Mr3 - Mn3);
            Lr0 = Lr0 * c0 + Lc0; o[0] *= c0; Mr0 = Mn0;
            Lr1 = Lr1 * c1 + Lc1; o[1] *= c1; Mr1 = Mn1;
            Lr2 = Lr2 * c2 + Lc2; o[2] *= c2; Mr2 = Mn2;
            Lr3 = Lr3 * c3 + Lc3; o[3] *= c3; Mr3 = Mn3;
        }

        // ========== phase 2: PV accumulation (coalesced, token per half-wave) ==========
        {
            int t = clo + hw;
            f4 vv = {}, vn = {};
            if (t < chi)
                vv = *(const f4*)(tok_base(vc, vcur, btrow, t, T, b, h) + d0v);
            if (t + 8 < chi)
                vn = *(const f4*)(tok_base(vc, vcur, btrow, t + 8, T, b, h) + d0v);
            for (; t < chi; t += 8) {
                f4 v2 = {};
                if (t + 16 < chi)
                    v2 = *(const f4*)(tok_base(vc, vcur, btrow, t + 16, T, b, h) + d0v);
                f4 p4 = *(const f4*)&sc[(t - clo) * 4];   // broadcast read
                o[0] += p4.x * vv;
                o[1] += p4.y * vv;
                o[2] += p4.z * vv;
                o[3] += p4.w * vv;
                vv = vn; vn = v2;
            }
        }
        __syncthreads();   // protect sc before next chunk's phase 1
    }

    // --- combine half-waves (plain sums: same normalization everywhere) ---
#pragma unroll
    for (int gg = 0; gg < 4; ++gg) {
        o[gg].x += __shfl_xor(o[gg].x, 32);
        o[gg].y += __shfl_xor(o[gg].y, 32);
        o[gg].z += __shfl_xor(o[gg].z, 32);
        o[gg].w += __shfl_xor(o[gg].w, 32);
    }
    if ((tid & 32) == 0) {
#pragma unroll
        for (int gg = 0; gg < 4; ++gg)
            *(f4*)(&lodata[w][gg][d0v]) = o[gg];
    }
    __syncthreads();

    {
        const int d  = tid & 127;
        const int g0 = tid >> 7;       // 0 or 1; handles heads g0 and g0+2
        const float LrA = (g0 == 0) ? Lr0 : Lr1;
        const float LrB = (g0 == 0) ? Lr2 : Lr3;
        const float MrA = (g0 == 0) ? Mr0 : Mr1;
        const float MrB = (g0 == 0) ? Mr2 : Mr3;

        float OA = lodata[0][g0][d] + lodata[1][g0][d] + lodata[2][g0][d] + lodata[3][g0][d];
        float OB = lodata[0][g0 + 2][d] + lodata[1][g0 + 2][d] + lodata[2][g0 + 2][d] + lodata[3][g0 + 2][d];

        if (S == 1) {
            out[(size_t)b * (NQH * HD) + (size_t)(h * GQA + g0) * HD + d]     = OA / LrA;
            out[(size_t)b * (NQH * HD) + (size_t)(h * GQA + g0 + 2) * HD + d] = OB / LrB;
        } else {
            int pidxA = blockIdx.x * 4 + g0;
            int pidxB = blockIdx.x * 4 + g0 + 2;
            po[(size_t)pidxA * HD + d] = OA;
            po[(size_t)pidxB * HD + d] = OB;
            if (d == 0) {
                pm[pidxA] = MrA; pl[pidxA] = LrA;
                pm[pidxB] = MrB; pl[pidxB] = LrB;
            }
        }
    }
}

__global__ void combine_kernel(
    const float* __restrict__ pm,
    const float* __restrict__ pl,
    const float* __restrict__ po,
    float* __restrict__ out, int S)
{
    int i = blockIdx.x * blockDim.x + threadIdx.x;   // over B*NQH*HD
    int d  = i & 127;
    int qh = (i >> 7) & 31;
    int b  = i >> 12;
    int h  = qh >> 2;
    int g  = qh & 3;
    int base = ((b * NKVH + h) * S) * 4 + g;
    float M = -INFINITY;
    for (int s = 0; s < S; ++s) M = fmaxf(M, pm[base + s * 4]);
    float L = 0.f, O = 0.f;
    for (int s = 0; s < S; ++s) {
        float wgt = __expf(pm[base + s * 4] - M);
        L += wgt * pl[base + s * 4];
        O += wgt * po[(size_t)(base + s * 4) * HD + d];
    }
    out[i] = O / L;
}

extern "C" void kernel_launch(void* const* d_in, const int* in_sizes, int n_in,
                              void* d_out, int out_size, void* d_ws, size_t ws_size,
                              hipStream_t stream) {
    const float* q  = (const float*)d_in[0];
    const float* k  = (const float*)d_in[1];
    const float* v  = (const float*)d_in[2];
    const float* kc = (const float*)d_in[3];
    const float* vc = (const float*)d_in[4];
    const int*   bt = (const int*)d_in[5];
    int B  = in_sizes[0] / (NQH * HD);
    int nb = in_sizes[5] / B;
    int T  = nb * PBLK;

    float* out = (float*)d_out;
    char*  ws  = (char*)d_ws;

    size_t tabBytes = (size_t)(T + 1) * 128 * sizeof(float);
    size_t off = (tabBytes + 255) & ~(size_t)255;

    int total = T + 1;
    int S = (total + CHUNK - 1) / CHUNK;     // one chunk per split
    if (S < 1) S = 1;
    int nblk = B * NKVH * S;
    size_t pmB = (size_t)nblk * 4 * sizeof(float);
    size_t poB = (size_t)nblk * 4 * HD * sizeof(float);
    size_t need = off + 2 * pmB + poB;

    int useTable = (ws_size >= tabBytes) ? 1 : 0;
    if (ws_size < need) S = 1;   // in-block chunk loop handles the full span

    float* tab = (float*)ws;
    float* pm  = (float*)(ws + off);
    float* pl  = (float*)(ws + off + pmB);
    float* po  = (float*)(ws + off + 2 * pmB);

    if (useTable) {
        int tot = (T + 1) * 64;
        rope_table_kernel<<<(tot + 255) / 256, 256, 0, stream>>>(tab, T);
    }
    paged_attn_kernel<<<B * NKVH * S, 256, 0, stream>>>(
        q, k, v, kc, vc, bt, tab, out, pm, pl, po, T, nb, S, useTable);
    if (S > 1) {
        int totalOut = B * NQH * HD;
        combine_kernel<<<(totalOut + 255) / 256, 256, 0, stream>>>(pm, pl, po, out, S);
    }
}